// Round 14
// baseline (1658.633 us; speedup 1.0000x reference)
//
#include <hip/hip_runtime.h>
#include <math.h>
#include <stdint.h>

typedef _Float16 f16;
typedef _Float16 f16x8 __attribute__((ext_vector_type(8)));
typedef float    f32x16 __attribute__((ext_vector_type(16)));

#define NBLK 256
#define NTHR 512
#define MROW 64

// ---- d_ws fragment layout (identical to r6-r13, validated) ----
#define FC1_F 512
#define FC2_F 640
#define ENC_F 656
#define TOT_F 1232
#define TOT_E (TOT_F*512)

#define MFMA32(a,b,c) __builtin_amdgcn_mfma_f32_32x32x16_f16((a),(b),(c),0,0,0)
#define LGKM0() asm volatile("s_waitcnt lgkmcnt(0)" ::: "memory")
#define BARR()  do { __builtin_amdgcn_s_barrier(); asm volatile("" ::: "memory"); } while(0)

__device__ __forceinline__ float sigm(float v){
  return __fdividef(1.0f, 1.0f + __expf(-v));
}
__device__ __forceinline__ float tanh_f(float v){
  float t = fminf(v, 8.0f);
  float e = __expf(2.0f * t);
  return 1.0f - 2.0f * __fdividef(1.0f, e + 1.0f);
}
__device__ __forceinline__ int eX(int row, int k){ return row*128 + (k ^ ((row & 7) << 3)); }

// ---------------- prep: pack weights as fp16 32x32x16 B-fragments (byte-identical r6-r13) ----------------
__global__ void prep_pack(const float* __restrict__ eWih, const float* __restrict__ eWhh,
                          const float* __restrict__ dWih, const float* __restrict__ dWhh,
                          const float* __restrict__ f1W,  const float* __restrict__ f2W,
                          f16* __restrict__ ws16)
{
  int idx = blockIdx.x * 256 + threadIdx.x;
  if (idx >= TOT_E) return;
  int frag = idx >> 9;
  int lo   = idx & 511;
  int l    = lo >> 3;
  int jj   = lo & 7;
  int c32  = l & 31;
  int half = l >> 5;
  int kin  = half*8 + jj;
  float v = 0.0f;
  if (frag < FC1_F){
    int ct = frag >> 6, st = (frag >> 4) & 3, ks = frag & 15;
    int col = ct*32 + c32, k = ks*16 + kin;
    if      (st == 0) v = dWih[col*256 + k]        + dWhh[col*256 + k];
    else if (st == 1) v = dWih[(256+col)*256 + k]  + dWhh[(256+col)*256 + k];
    else if (st == 2) v = dWih[(512+col)*256 + k];
    else              v = dWhh[(512+col)*256 + k];
  } else if (frag < FC2_F){
    int f = frag - FC1_F, ct = f >> 4, ks = f & 15;
    int col = ct*32 + c32, k = ks*16 + kin;
    v = f1W[col*256 + k];
  } else if (frag < ENC_F){
    int ks = frag - FC2_F, k = ks*16 + kin;
    v = (c32 < 2) ? f2W[c32*256 + k] : 0.0f;
  } else {
    int f = frag - ENC_F, ct = f / 72, r = f % 72;
    int col = ct*32 + c32;
    if (r < 24){ int st = r >> 3, ks = r & 7;  v = eWih[(st*256 + col)*128 + ks*16 + kin]; }
    else { r -= 24; int st = r >> 4, ks = r & 15; v = eWhh[(st*256 + col)*256 + ks*16 + kin]; }
  }
  ws16[idx] = (f16)v;
}

// ---------------- fused persistent kernel: 2-pass GRU, register-B depth-4 pipe ----------------
__global__ __launch_bounds__(NTHR, 1)
void fused_net(const float* __restrict__ x,
               const float* __restrict__ emW, const float* __restrict__ emb_,
               const float* __restrict__ evW, const float* __restrict__ evb,
               const float* __restrict__ ebih, const float* __restrict__ ebhh,
               const float* __restrict__ dbih, const float* __restrict__ dbhh,
               const float* __restrict__ f1b, const float* __restrict__ f2b,
               const f16* __restrict__ ws16, float* __restrict__ out)
{
  __shared__ __align__(16) f16 H0[16384];    // [64][256] h ping
  __shared__ __align__(16) f16 H1[16384];    // [64][256] h pong / fc1-out
  __shared__ __align__(16) f16 xbuf[8192];   // encoder xt [64][128]

  const int tid  = threadIdx.x;
  const int r0   = blockIdx.x * MROW;
  const int l    = tid & 63;
  const int wu   = __builtin_amdgcn_readfirstlane(tid >> 6);  // wave-uniform col-tile 0..7
  const int c32  = l & 31;
  const int half = l >> 5;
  const int lo8  = l << 3;                   // per-lane f16-element offset into fragments

  f16* hp = H0;
  f16* hq = H1;

  const int abase = c32*256 + ((half*8) ^ ((l & 7) << 3));
  const int xab   = c32*128 + ((half*8) ^ ((l & 7) << 3));
  const int colm  = wu*32 + c32;

  // wave-uniform weight bases (SGPR) + per-lane lo8
  const f16* wdec = ws16 + (size_t)(wu*64)*512;
  const f16* wfc1 = ws16 + (size_t)(FC1_F + wu*16)*512;
  const f16* wfc2 = ws16 + (size_t)FC2_F*512;
  const f16* wenc = ws16 + (size_t)(ENC_F + wu*72)*512;

  #define LDW(base, frag) (*(const f16x8*)((base) + (size_t)(frag)*512 + lo8))

  // batch loaders; n is compile-time constant at every call site (unrolled loops)
  auto encb = [&](int n, f16x8* d){
    if (n < 8)      {                  d[0] = LDW(wenc, n);        d[1] = LDW(wenc, 8 + n); }       // x: r,z k=n
    else if (n < 24){ int k = n - 8;   d[0] = LDW(wenc, 24 + k);   d[1] = LDW(wenc, 40 + k); }      // h: r,z k
    else if (n < 28){ int j = 2*(n-24);d[0] = LDW(wenc, 16 + j);   d[1] = LDW(wenc, 17 + j); }      // x: n pair
    else            { int k = 2*(n-28);d[0] = LDW(wenc, 56 + k);   d[1] = LDW(wenc, 57 + k); }      // h: hn pair
  };
  auto decb = [&](int n, f16x8* d){
    if (n < 16)      {               d[0] = LDW(wdec, n);        d[1] = LDW(wdec, 16 + n); }        // r,z k=n
    else if (n < 32) { int k = n-16; d[0] = LDW(wdec, 32 + k);   d[1] = LDW(wdec, 48 + k); }        // in,hn k
    else             { int f = n-32; d[0] = LDW(wfc1, 2*f);      d[1] = LDW(wfc1, 2*f + 1); }       // fc1 pair
  };

  // depth-4 register pipe; all indices static (unrolled loops) -> stays in VGPRs
  f16x8 bq[4][2];
  #pragma unroll
  for (int p = 0; p < 4; ++p) encb(p, bq[p]);

  for (int i = tid; i < 16384; i += NTHR) H0[i] = (f16)0.0f;   // h0 = 0

  // =============== ENCODER: 9 GRU steps, 2-pass ===============
  {
    const float ebr = ebih[colm]       + ebhh[colm];
    const float ebz = ebih[256 + colm] + ebhh[256 + colm];
    const float ebn = ebih[512 + colm];
    const float ebh = ebhh[512 + colm];

    #pragma unroll 1
    for (int t = 0; t < 9; ++t){
      const bool tlt8 = (t < 8);
      { // xt = tanh(embedding) -> xbuf
        int e  = tid & 127;
        int rq = tid >> 7;
        const float* Wp = tlt8 ? (evW + e*6) : (emW + e*6);
        float bb = tlt8 ? evb[e] : emb_[e];
        float w0 = Wp[0], w1 = Wp[1], w2 = Wp[2], w3 = Wp[3], w4 = Wp[4], w5 = Wp[5];
        int xo = tlt8 ? (6 + t*6) : 0;
        #pragma unroll 1
        for (int rr = 0; rr < 16; ++rr){
          int row = rq*16 + rr;
          const float* xs = x + (size_t)(r0 + row)*54 + xo;
          float a = bb + xs[0]*w0 + xs[1]*w1 + xs[2]*w2 + xs[3]*w3 + xs[4]*w4 + xs[5]*w5;
          xbuf[eX(row, e)] = (f16)tanh_f(a);
        }
      }
      LGKM0(); BARR();   // xbuf (and t=0: H0 init) visible

      f32x16 rvv[2], zvv[2];
      { // ---- pass 1: r,z; units 0..23 consume batches 0..23 ----
        f32x16 aR[2], aZ[2];
        aR[0]=0.f; aR[1]=0.f; aZ[0]=0.f; aZ[1]=0.f;
        #pragma unroll
        for (int u = 0; u < 24; ++u){
          f16x8 b0 = bq[u & 3][0];
          f16x8 b1 = bq[u & 3][1];
          encb(u + 4, bq[u & 3]);                 // u+4 <= 27 < 36: no wrap in pass 1
          if (u < 8){
            int ao = xab ^ (u << 4);
            f16x8 a0 = *(const f16x8*)(xbuf + ao);
            f16x8 a1 = *(const f16x8*)(xbuf + ao + 4096);
            aR[0]=MFMA32(a0,b0,aR[0]); aR[1]=MFMA32(a1,b0,aR[1]);
            aZ[0]=MFMA32(a0,b1,aZ[0]); aZ[1]=MFMA32(a1,b1,aZ[1]);
          } else {
            int ao = abase ^ ((u - 8) << 4);
            f16x8 a0 = *(const f16x8*)(hp + ao);
            f16x8 a1 = *(const f16x8*)(hp + ao + 8192);
            aR[0]=MFMA32(a0,b0,aR[0]); aR[1]=MFMA32(a1,b0,aR[1]);
            aZ[0]=MFMA32(a0,b1,aZ[0]); aZ[1]=MFMA32(a1,b1,aZ[1]);
          }
        }
        #pragma unroll
        for (int rt = 0; rt < 2; ++rt)
          #pragma unroll
          for (int rg = 0; rg < 16; ++rg){
            rvv[rt][rg] = sigm(aR[rt][rg] + ebr);
            zvv[rt][rg] = sigm(aZ[rt][rg] + ebz);
          }
      }
      { // ---- pass 2: n,hn; units 24..35 consume batches 24..35 (2 k-steps each) ----
        f32x16 aN[2], aH[2];
        aN[0]=0.f; aN[1]=0.f; aH[0]=0.f; aH[1]=0.f;
        #pragma unroll
        for (int m = 0; m < 12; ++m){
          f16x8 b0 = bq[m & 3][0];                // slot (24+m)&3 == m&3
          f16x8 b1 = bq[m & 3][1];
          if (m < 8) encb(28 + m, bq[m & 3]);     // batches 28..35
          else if (tlt8) encb(m - 8, bq[m & 3]);  // wrap: next enc step batches 0..3
          else decb(m - 8, bq[m & 3]);            // wrap: decoder batches 0..3
          if (m < 4){
            int j = 2*m;
            int ao0 = xab ^ (j << 4), ao1 = xab ^ ((j+1) << 4);
            f16x8 a0 = *(const f16x8*)(xbuf + ao0);
            f16x8 a1 = *(const f16x8*)(xbuf + ao0 + 4096);
            aN[0]=MFMA32(a0,b0,aN[0]); aN[1]=MFMA32(a1,b0,aN[1]);
            f16x8 a2 = *(const f16x8*)(xbuf + ao1);
            f16x8 a3 = *(const f16x8*)(xbuf + ao1 + 4096);
            aN[0]=MFMA32(a2,b1,aN[0]); aN[1]=MFMA32(a3,b1,aN[1]);
          } else {
            int k = 2*(m-4);
            int ao0 = abase ^ (k << 4), ao1 = abase ^ ((k+1) << 4);
            f16x8 a0 = *(const f16x8*)(hp + ao0);
            f16x8 a1 = *(const f16x8*)(hp + ao0 + 8192);
            aH[0]=MFMA32(a0,b0,aH[0]); aH[1]=MFMA32(a1,b0,aH[1]);
            f16x8 a2 = *(const f16x8*)(hp + ao1);
            f16x8 a3 = *(const f16x8*)(hp + ao1 + 8192);
            aH[0]=MFMA32(a2,b1,aH[0]); aH[1]=MFMA32(a3,b1,aH[1]);
          }
        }
        // epilogue -> hq
        #pragma unroll
        for (int rt = 0; rt < 2; ++rt){
          #pragma unroll
          for (int rg = 0; rg < 16; ++rg){
            int rr  = (rg & 3) + 8*(rg >> 2) + 4*half;
            int row = rt*32 + rr;
            int el  = row*256 + (colm ^ ((rr & 7) << 3));
            float nv = tanh_f(aN[rt][rg] + ebn + rvv[rt][rg]*(aH[rt][rg] + ebh));
            float ho = (float)hp[el];
            hq[el] = (f16)(nv + zvv[rt][rg]*(ho - nv));
          }
        }
      }
      LGKM0(); BARR();
      { f16* tmp = hp; hp = hq; hq = tmp; }
    }
  }

  // =============== DECODER: 32 x (2-pass GRU + fc1 + fc2) ===============
  const float dbr = dbih[colm]       + dbhh[colm];
  const float dbz = dbih[256 + colm] + dbhh[256 + colm];
  const float dbn = dbih[512 + colm];
  const float dbh = dbhh[512 + colm];
  const float f1bb = f1b[colm];
  const float f2bb = (c32 < 2) ? f2b[c32] : 0.0f;

  #pragma unroll 1
  for (int s = 0; s < 32; ++s){
    f32x16 rvv[2], zvv[2];
    { // ---- GRU pass A: r,z (units 0..15), reads hp ----
      f32x16 aR[2], aZ[2];
      aR[0]=0.f; aR[1]=0.f; aZ[0]=0.f; aZ[1]=0.f;
      #pragma unroll
      for (int u = 0; u < 16; ++u){
        f16x8 b0 = bq[u & 3][0];
        f16x8 b1 = bq[u & 3][1];
        decb(u + 4, bq[u & 3]);                  // batches 4..19
        int ao = abase ^ (u << 4);
        f16x8 a0 = *(const f16x8*)(hp + ao);
        f16x8 a1 = *(const f16x8*)(hp + ao + 8192);
        aR[0]=MFMA32(a0,b0,aR[0]); aR[1]=MFMA32(a1,b0,aR[1]);
        aZ[0]=MFMA32(a0,b1,aZ[0]); aZ[1]=MFMA32(a1,b1,aZ[1]);
      }
      #pragma unroll
      for (int rt = 0; rt < 2; ++rt)
        #pragma unroll
        for (int rg = 0; rg < 16; ++rg){
          rvv[rt][rg] = sigm(aR[rt][rg] + dbr);
          zvv[rt][rg] = sigm(aZ[rt][rg] + dbz);
        }
    }
    { // ---- GRU pass B: n,hn (units 16..31), reads hp, writes h_new -> hq ----
      f32x16 aN[2], aH[2];
      aN[0]=0.f; aN[1]=0.f; aH[0]=0.f; aH[1]=0.f;
      #pragma unroll
      for (int u = 16; u < 32; ++u){
        f16x8 b0 = bq[u & 3][0];
        f16x8 b1 = bq[u & 3][1];
        decb(u + 4, bq[u & 3]);                  // batches 20..35
        int k = u - 16;
        int ao = abase ^ (k << 4);
        f16x8 a0 = *(const f16x8*)(hp + ao);
        f16x8 a1 = *(const f16x8*)(hp + ao + 8192);
        aN[0]=MFMA32(a0,b0,aN[0]); aN[1]=MFMA32(a1,b0,aN[1]);
        aH[0]=MFMA32(a0,b1,aH[0]); aH[1]=MFMA32(a1,b1,aH[1]);
      }
      #pragma unroll
      for (int rt = 0; rt < 2; ++rt){
        #pragma unroll
        for (int rg = 0; rg < 16; ++rg){
          int rr  = (rg & 3) + 8*(rg >> 2) + 4*half;
          int row = rt*32 + rr;
          int el  = row*256 + (colm ^ ((rr & 7) << 3));
          float nv = tanh_f(aN[rt][rg] + dbn + rvv[rt][rg]*(aH[rt][rg] + dbh));
          float ho = (float)hp[el];
          hq[el] = (f16)(nv + zvv[rt][rg]*(ho - nv));
        }
      }
    }
    LGKM0(); BARR();

    { // ---- FC1 (units 32..39, 2 k-steps each): reads hq, writes -> hp ----
      f32x16 aF[2];
      aF[0]=0.f; aF[1]=0.f;
      #pragma unroll
      for (int u = 32; u < 40; ++u){
        f16x8 b0 = bq[u & 3][0];
        f16x8 b1 = bq[u & 3][1];
        if (u + 4 < 40) decb(u + 4, bq[u & 3]);  // batches 36..39
        else            decb(u - 36, bq[u & 3]); // wrap: next step batches 0..3
        int f = u - 32;
        int k0 = 2*f;
        int ao0 = abase ^ (k0 << 4), ao1 = abase ^ ((k0+1) << 4);
        f16x8 a0 = *(const f16x8*)(hq + ao0);
        f16x8 a1 = *(const f16x8*)(hq + ao0 + 8192);
        aF[0]=MFMA32(a0,b0,aF[0]); aF[1]=MFMA32(a1,b0,aF[1]);
        f16x8 a2 = *(const f16x8*)(hq + ao1);
        f16x8 a3 = *(const f16x8*)(hq + ao1 + 8192);
        aF[0]=MFMA32(a2,b1,aF[0]); aF[1]=MFMA32(a3,b1,aF[1]);
      }
      #pragma unroll
      for (int rt = 0; rt < 2; ++rt){
        #pragma unroll
        for (int rg = 0; rg < 16; ++rg){
          int rr  = (rg & 3) + 8*(rg >> 2) + 4*half;
          int row = rt*32 + rr;
          int el  = row*256 + (colm ^ ((rr & 7) << 3));
          hp[el] = (f16)fmaxf(aF[rt][rg] + f1bb, 0.0f);
        }
      }
    }
    LGKM0(); BARR();

    // ---- FC2 (waves 0-1, one 32-row tile each): y = tanh(fc1out @ W2.T + b2) -> out ----
    if (wu < 2){
      f32x16 a2 = 0.f;
      f16x8 c0 = LDW(wfc2, 0), c1 = LDW(wfc2, 1), c2 = LDW(wfc2, 2), c3 = LDW(wfc2, 3);
      const int rb = wu * 8192;
      #pragma unroll
      for (int g = 0; g < 4; ++g){
        f16x8 u0 = c0, u1 = c1, u2 = c2, u3 = c3;
        if (g < 3){
          c0 = LDW(wfc2, (g+1)*4 + 0);
          c1 = LDW(wfc2, (g+1)*4 + 1);
          c2 = LDW(wfc2, (g+1)*4 + 2);
          c3 = LDW(wfc2, (g+1)*4 + 3);
        }
        int kb = g*4;
        f16x8 a0 = *(const f16x8*)(hp + ((abase + rb) ^ ((kb + 0) << 4)));
        a2 = MFMA32(a0, u0, a2);
        f16x8 a1 = *(const f16x8*)(hp + ((abase + rb) ^ ((kb + 1) << 4)));
        a2 = MFMA32(a1, u1, a2);
        f16x8 av2 = *(const f16x8*)(hp + ((abase + rb) ^ ((kb + 2) << 4)));
        a2 = MFMA32(av2, u2, a2);
        f16x8 a3 = *(const f16x8*)(hp + ((abase + rb) ^ ((kb + 3) << 4)));
        a2 = MFMA32(a3, u3, a2);
      }
      if (c32 < 2){
        #pragma unroll
        for (int rg = 0; rg < 16; ++rg){
          int rr = (rg & 3) + 8*(rg >> 2) + 4*half;
          out[((size_t)(r0 + wu*32 + rr)*32 + s)*2 + c32] = tanh_f(a2[rg] + f2bb);
        }
      }
    }
    BARR();   // next pass-B writes the fc1out buffer; FC2 must finish first
    { f16* tmp = hp; hp = hq; hq = tmp; }
  }
  #undef LDW
}

extern "C" void kernel_launch(void* const* d_in, const int* in_sizes, int n_in,
                              void* d_out, int out_size, void* d_ws, size_t ws_size,
                              hipStream_t stream)
{
  (void)in_sizes; (void)n_in; (void)out_size; (void)ws_size;
  const float* x    = (const float*)d_in[0];
  const float* emW  = (const float*)d_in[1];
  const float* emb_ = (const float*)d_in[2];
  const float* evW  = (const float*)d_in[3];
  const float* evb  = (const float*)d_in[4];
  const float* eWih = (const float*)d_in[5];
  const float* eWhh = (const float*)d_in[6];
  const float* ebih = (const float*)d_in[7];
  const float* ebhh = (const float*)d_in[8];
  const float* dWih = (const float*)d_in[9];
  const float* dWhh = (const float*)d_in[10];
  const float* dbih = (const float*)d_in[11];
  const float* dbhh = (const float*)d_in[12];
  const float* f1W  = (const float*)d_in[13];
  const float* f1b  = (const float*)d_in[14];
  const float* f2W  = (const float*)d_in[15];
  const float* f2b  = (const float*)d_in[16];
  float* out = (float*)d_out;
  f16* ws16 = (f16*)d_ws;

  prep_pack<<<(TOT_E + 255)/256, 256, 0, stream>>>(eWih, eWhh, dWih, dWhh, f1W, f2W, ws16);
  fused_net<<<NBLK, NTHR, 0, stream>>>(x, emW, emb_, evW, evb, ebih, ebhh,
                                       dbih, dbhh, f1b, f2b, ws16, out);
}

// Round 15
// 748.442 us; speedup vs baseline: 2.2161x; 2.2161x over previous
//
#include <hip/hip_runtime.h>
#include <math.h>
#include <stdint.h>

typedef _Float16 f16;
typedef _Float16 f16x8 __attribute__((ext_vector_type(8)));
typedef float    f32x16 __attribute__((ext_vector_type(16)));

#define NBLK 256
#define NTHR 512
#define MROW 64

// ---- d_ws layout: LINEAR consumption-order streams (1 frag = 512 f16 = 1KB, 1 batch = 2 frags) ----
// DEC stream:  frags [0,640):    ct*80 + n*2 + j   (n 0..39: 0-15 r/z, 16-31 in/hn, 32-39 fc1 pairs)
// ENC stream:  frags [640,1216): 640 + ct*72 + n*2 + j (n 0..35: 0-7 x r/z, 8-23 h r/z, 24-27 x n-pairs, 28-35 h hn-pairs)
// FC2:         frags [1216,1232)
#define ENCS 640
#define FC2S 1216
#define TOT_F 1232
#define TOT_E (TOT_F*512)

#define MFMA32(a,b,c) __builtin_amdgcn_mfma_f32_32x32x16_f16((a),(b),(c),0,0,0)
#define VMW4()  asm volatile("s_waitcnt vmcnt(4)" ::: "memory")
#define LGKM0() asm volatile("s_waitcnt lgkmcnt(0)" ::: "memory")
#define BARR()  do { __builtin_amdgcn_s_barrier(); asm volatile("" ::: "memory"); } while(0)

__device__ __forceinline__ void gld16(const f16* g, f16* lds){
  __builtin_amdgcn_global_load_lds(
      (const __attribute__((address_space(1))) void*)(uintptr_t)(const void*)g,
      (__attribute__((address_space(3))) void*)(uint32_t)(uintptr_t)(void*)lds,
      16, 0, 0);
}

__device__ __forceinline__ float sigm(float v){
  return __fdividef(1.0f, 1.0f + __expf(-v));
}
__device__ __forceinline__ float tanh_f(float v){
  float t = fminf(v, 8.0f);
  float e = __expf(2.0f * t);
  return 1.0f - 2.0f * __fdividef(1.0f, e + 1.0f);
}
__device__ __forceinline__ int eX(int row, int k){ return row*128 + (k ^ ((row & 7) << 3)); }

// ---------------- prep: pack weights into linear consumption-order streams ----------------
__global__ void prep_pack(const float* __restrict__ eWih, const float* __restrict__ eWhh,
                          const float* __restrict__ dWih, const float* __restrict__ dWhh,
                          const float* __restrict__ f1W,  const float* __restrict__ f2W,
                          f16* __restrict__ ws16)
{
  int idx = blockIdx.x * 256 + threadIdx.x;
  if (idx >= TOT_E) return;
  int frag = idx >> 9;
  int lo   = idx & 511;
  int l    = lo >> 3;
  int jj   = lo & 7;
  int c32  = l & 31;
  int half = l >> 5;
  int kin  = half*8 + jj;
  float v = 0.0f;
  if (frag < ENCS){                        // decoder stream
    int ct = frag / 80, r80 = frag % 80, n = r80 >> 1, j = r80 & 1;
    int col = ct*32 + c32;
    if (n < 16){ int k = n*16 + kin;
      v = (j == 0) ? (dWih[col*256 + k]       + dWhh[col*256 + k])
                   : (dWih[(256+col)*256 + k] + dWhh[(256+col)*256 + k]);
    } else if (n < 32){ int k = (n-16)*16 + kin;
      v = (j == 0) ? dWih[(512+col)*256 + k] : dWhh[(512+col)*256 + k];
    } else { int ks = (n-32)*2 + j; int k = ks*16 + kin;
      v = f1W[col*256 + k];
    }
  } else if (frag < FC2S){                 // encoder stream
    int f = frag - ENCS;
    int ct = f / 72, r = f % 72, n = r >> 1, j = r & 1;
    int col = ct*32 + c32;
    if (n < 8)       { int k = n*16 + kin;       v = eWih[(j*256 + col)*128 + k]; }
    else if (n < 24) { int k = (n-8)*16 + kin;   v = eWhh[(j*256 + col)*256 + k]; }
    else if (n < 28) { int ks = (n-24)*2 + j;    v = eWih[(512 + col)*128 + ks*16 + kin]; }
    else             { int ks = (n-28)*2 + j;    v = eWhh[(512 + col)*256 + ks*16 + kin]; }
  } else {                                 // fc2 (cols >=2 zero)
    int ks = frag - FC2S; int k = ks*16 + kin;
    v = (c32 < 2) ? f2W[c32*256 + k] : 0.0f;
  }
  ws16[idx] = (f16)v;
}

// ---------------- fused persistent kernel: 2-pass GRU, linear DMA streams ----------------
__global__ __launch_bounds__(NTHR, 1)
void fused_net(const float* __restrict__ x,
               const float* __restrict__ emW, const float* __restrict__ emb_,
               const float* __restrict__ evW, const float* __restrict__ evb,
               const float* __restrict__ ebih, const float* __restrict__ ebhh,
               const float* __restrict__ dbih, const float* __restrict__ dbhh,
               const float* __restrict__ f1b, const float* __restrict__ f2b,
               const f16* __restrict__ ws16, float* __restrict__ out)
{
  __shared__ __align__(16) f16 H0[16384];    // [64][256] h ping
  __shared__ __align__(16) f16 H1[16384];    // [64][256] h pong / fc1-out
  __shared__ __align__(16) f16 stg[32768];   // 8 waves x 4 slots x 1024 f16
  __shared__ __align__(16) f16 xbuf[8192];   // encoder xt [64][128]

  const int tid  = threadIdx.x;
  const int r0   = blockIdx.x * MROW;
  const int l    = tid & 63;
  const int wu   = __builtin_amdgcn_readfirstlane(tid >> 6);
  const int c32  = l & 31;
  const int half = l >> 5;
  const int lo8  = l << 3;

  f16* hp = H0;
  f16* hq = H1;

  const int abase = c32*256 + ((half*8) ^ ((l & 7) << 3));
  const int xab   = c32*128 + ((half*8) ^ ((l & 7) << 3));
  const int colm  = wu*32 + c32;

  f16* slot0 = stg + wu*4096;                // wave-private 4 x 1KB-frag-pair slots

  const f16* gdec = ws16 + (size_t)(wu*80)*512          + lo8;
  const f16* genc = ws16 + (size_t)(ENCS + wu*72)*512   + lo8;
  const f16* gfc2 = ws16 + (size_t)FC2S*512             + lo8;

  auto issue = [&](const f16* sb, int n, int q){
    f16* d = slot0 + q*1024;
    const f16* g = sb + (size_t)n*1024;
    gld16(g, d);
    gld16(g + 512, d + 512);
  };

  // prologue: encoder batches 0,1,2 in flight
  issue(genc, 0, 0); issue(genc, 1, 1); issue(genc, 2, 2);

  for (int i = tid; i < 16384; i += NTHR) H0[i] = (f16)0.0f;   // h0 = 0

  // =============== ENCODER: 9 GRU steps, 2-pass ===============
  {
    const float ebr = ebih[colm]       + ebhh[colm];
    const float ebz = ebih[256 + colm] + ebhh[256 + colm];
    const float ebn = ebih[512 + colm];
    const float ebh = ebhh[512 + colm];

    #pragma unroll 1
    for (int t = 0; t < 9; ++t){
      const bool tlt8 = (t < 8);
      { // xt = tanh(embedding) -> xbuf
        int e  = tid & 127;
        int rq = tid >> 7;
        const float* Wp = tlt8 ? (evW + e*6) : (emW + e*6);
        float bb = tlt8 ? evb[e] : emb_[e];
        float w0 = Wp[0], w1 = Wp[1], w2 = Wp[2], w3 = Wp[3], w4 = Wp[4], w5 = Wp[5];
        int xo = tlt8 ? (6 + t*6) : 0;
        #pragma unroll 1
        for (int rr = 0; rr < 16; ++rr){
          int row = rq*16 + rr;
          const float* xs = x + (size_t)(r0 + row)*54 + xo;
          float a = bb + xs[0]*w0 + xs[1]*w1 + xs[2]*w2 + xs[3]*w3 + xs[4]*w4 + xs[5]*w5;
          xbuf[eX(row, e)] = (f16)tanh_f(a);
        }
      }
      LGKM0(); BARR();   // xbuf (and t=0: H0 init) visible

      f32x16 rvv[2], zvv[2];
      { // ---- pass 1: r,z; units 0..23 (batch u = (r,z) slice) ----
        f32x16 aR[2], aZ[2];
        aR[0]=0.f; aR[1]=0.f; aZ[0]=0.f; aZ[1]=0.f;
        #pragma unroll 4
        for (int u = 0; u < 24; ++u){
          VMW4();
          issue(genc, u + 3, (u + 3) & 3);     // 3..26, no wrap
          const f16* sp = slot0 + (u & 3)*1024;
          f16x8 b0 = *(const f16x8*)(sp + lo8);
          f16x8 b1 = *(const f16x8*)(sp + 512 + lo8);
          if (u < 8){
            int ao = xab ^ (u << 4);
            f16x8 a0 = *(const f16x8*)(xbuf + ao);
            f16x8 a1 = *(const f16x8*)(xbuf + ao + 4096);
            aR[0]=MFMA32(a0,b0,aR[0]); aR[1]=MFMA32(a1,b0,aR[1]);
            aZ[0]=MFMA32(a0,b1,aZ[0]); aZ[1]=MFMA32(a1,b1,aZ[1]);
          } else {
            int ao = abase ^ ((u - 8) << 4);
            f16x8 a0 = *(const f16x8*)(hp + ao);
            f16x8 a1 = *(const f16x8*)(hp + ao + 8192);
            aR[0]=MFMA32(a0,b0,aR[0]); aR[1]=MFMA32(a1,b0,aR[1]);
            aZ[0]=MFMA32(a0,b1,aZ[0]); aZ[1]=MFMA32(a1,b1,aZ[1]);
          }
        }
        #pragma unroll
        for (int rt = 0; rt < 2; ++rt)
          #pragma unroll
          for (int rg = 0; rg < 16; ++rg){
            rvv[rt][rg] = sigm(aR[rt][rg] + ebr);
            zvv[rt][rg] = sigm(aZ[rt][rg] + ebz);
          }
      }
      { // ---- pass 2: n,hn; units 24..35, 2 k-steps per unit ----
        f32x16 aN[2], aH[2];
        aN[0]=0.f; aN[1]=0.f; aH[0]=0.f; aH[1]=0.f;
        #pragma unroll
        for (int m = 0; m < 12; ++m){
          int u = 24 + m;
          VMW4();
          int nn = u + 3;                       // 27..38
          if (nn < 36)      issue(genc, nn, nn & 3);
          else if (tlt8)    issue(genc, nn - 36, nn & 3);
          else              issue(gdec, nn - 36, nn & 3);
          const f16* sp = slot0 + (u & 3)*1024;
          f16x8 b0 = *(const f16x8*)(sp + lo8);
          f16x8 b1 = *(const f16x8*)(sp + 512 + lo8);
          if (m < 4){
            int j = 2*m;
            int ao0 = xab ^ (j << 4), ao1 = xab ^ ((j+1) << 4);
            f16x8 a0 = *(const f16x8*)(xbuf + ao0);
            f16x8 a1 = *(const f16x8*)(xbuf + ao0 + 4096);
            aN[0]=MFMA32(a0,b0,aN[0]); aN[1]=MFMA32(a1,b0,aN[1]);
            f16x8 a2 = *(const f16x8*)(xbuf + ao1);
            f16x8 a3 = *(const f16x8*)(xbuf + ao1 + 4096);
            aN[0]=MFMA32(a2,b1,aN[0]); aN[1]=MFMA32(a3,b1,aN[1]);
          } else {
            int k = 2*(m-4);
            int ao0 = abase ^ (k << 4), ao1 = abase ^ ((k+1) << 4);
            f16x8 a0 = *(const f16x8*)(hp + ao0);
            f16x8 a1 = *(const f16x8*)(hp + ao0 + 8192);
            aH[0]=MFMA32(a0,b0,aH[0]); aH[1]=MFMA32(a1,b0,aH[1]);
            f16x8 a2 = *(const f16x8*)(hp + ao1);
            f16x8 a3 = *(const f16x8*)(hp + ao1 + 8192);
            aH[0]=MFMA32(a2,b1,aH[0]); aH[1]=MFMA32(a3,b1,aH[1]);
          }
        }
        // epilogue -> hq
        #pragma unroll
        for (int rt = 0; rt < 2; ++rt){
          #pragma unroll
          for (int rg = 0; rg < 16; ++rg){
            int rr  = (rg & 3) + 8*(rg >> 2) + 4*half;
            int row = rt*32 + rr;
            int el  = row*256 + (colm ^ ((rr & 7) << 3));
            float nv = tanh_f(aN[rt][rg] + ebn + rvv[rt][rg]*(aH[rt][rg] + ebh));
            float ho = (float)hp[el];
            hq[el] = (f16)(nv + zvv[rt][rg]*(ho - nv));
          }
        }
      }
      LGKM0(); BARR();
      { f16* tmp = hp; hp = hq; hq = tmp; }
    }
  }

  // =============== DECODER: 32 x (2-pass GRU + fc1 + fc2) ===============
  const float dbr = dbih[colm]       + dbhh[colm];
  const float dbz = dbih[256 + colm] + dbhh[256 + colm];
  const float dbn = dbih[512 + colm];
  const float dbh = dbhh[512 + colm];
  const float f1bb = f1b[colm];
  const float f2bb = (c32 < 2) ? f2b[c32] : 0.0f;

  #pragma unroll 1
  for (int s = 0; s < 32; ++s){
    f32x16 rvv[2], zvv[2];
    { // ---- GRU pass A: r,z (units 0..15), reads hp ----
      f32x16 aR[2], aZ[2];
      aR[0]=0.f; aR[1]=0.f; aZ[0]=0.f; aZ[1]=0.f;
      #pragma unroll 4
      for (int u = 0; u < 16; ++u){
        VMW4();
        issue(gdec, u + 3, (u + 3) & 3);        // 3..18
        const f16* sp = slot0 + (u & 3)*1024;
        f16x8 b0 = *(const f16x8*)(sp + lo8);
        f16x8 b1 = *(const f16x8*)(sp + 512 + lo8);
        int ao = abase ^ (u << 4);
        f16x8 a0 = *(const f16x8*)(hp + ao);
        f16x8 a1 = *(const f16x8*)(hp + ao + 8192);
        aR[0]=MFMA32(a0,b0,aR[0]); aR[1]=MFMA32(a1,b0,aR[1]);
        aZ[0]=MFMA32(a0,b1,aZ[0]); aZ[1]=MFMA32(a1,b1,aZ[1]);
      }
      #pragma unroll
      for (int rt = 0; rt < 2; ++rt)
        #pragma unroll
        for (int rg = 0; rg < 16; ++rg){
          rvv[rt][rg] = sigm(aR[rt][rg] + dbr);
          zvv[rt][rg] = sigm(aZ[rt][rg] + dbz);
        }
    }
    BARR();   // (A|B): fences prev step's FC2 reads of the buffer pass B now writes

    { // ---- GRU pass B: n,hn (units 16..31), reads hp, writes h_new -> hq ----
      f32x16 aN[2], aH[2];
      aN[0]=0.f; aN[1]=0.f; aH[0]=0.f; aH[1]=0.f;
      #pragma unroll 4
      for (int u = 16; u < 32; ++u){
        VMW4();
        issue(gdec, u + 3, (u + 3) & 3);        // 19..34
        const f16* sp = slot0 + (u & 3)*1024;
        f16x8 b0 = *(const f16x8*)(sp + lo8);
        f16x8 b1 = *(const f16x8*)(sp + 512 + lo8);
        int k = u - 16;
        int ao = abase ^ (k << 4);
        f16x8 a0 = *(const f16x8*)(hp + ao);
        f16x8 a1 = *(const f16x8*)(hp + ao + 8192);
        aN[0]=MFMA32(a0,b0,aN[0]); aN[1]=MFMA32(a1,b0,aN[1]);
        aH[0]=MFMA32(a0,b1,aH[0]); aH[1]=MFMA32(a1,b1,aH[1]);
      }
      #pragma unroll
      for (int rt = 0; rt < 2; ++rt){
        #pragma unroll
        for (int rg = 0; rg < 16; ++rg){
          int rr  = (rg & 3) + 8*(rg >> 2) + 4*half;
          int row = rt*32 + rr;
          int el  = row*256 + (colm ^ ((rr & 7) << 3));
          float nv = tanh_f(aN[rt][rg] + dbn + rvv[rt][rg]*(aH[rt][rg] + dbh));
          float ho = (float)hp[el];
          hq[el] = (f16)(nv + zvv[rt][rg]*(ho - nv));
        }
      }
    }
    LGKM0(); BARR();   // (B|FC1)

    { // ---- FC1 (units 32..39, 2 k-steps each): reads hq, writes -> hp ----
      f32x16 aF[2];
      aF[0]=0.f; aF[1]=0.f;
      #pragma unroll
      for (int f = 0; f < 8; ++f){
        VMW4();
        int nn = 35 + f;                        // 35..42 -> wrap 0,1,2
        if (nn < 40) issue(gdec, nn, nn & 3);
        else         issue(gdec, nn - 40, nn & 3);
        const f16* sp = slot0 + (f & 3)*1024;   // (32+f)&3 == f&3
        f16x8 b0 = *(const f16x8*)(sp + lo8);
        f16x8 b1 = *(const f16x8*)(sp + 512 + lo8);
        int k0 = 2*f;
        int ao0 = abase ^ (k0 << 4), ao1 = abase ^ ((k0+1) << 4);
        f16x8 a0 = *(const f16x8*)(hq + ao0);
        f16x8 a1 = *(const f16x8*)(hq + ao0 + 8192);
        aF[0]=MFMA32(a0,b0,aF[0]); aF[1]=MFMA32(a1,b0,aF[1]);
        f16x8 a2 = *(const f16x8*)(hq + ao1);
        f16x8 a3 = *(const f16x8*)(hq + ao1 + 8192);
        aF[0]=MFMA32(a2,b1,aF[0]); aF[1]=MFMA32(a3,b1,aF[1]);
      }
      #pragma unroll
      for (int rt = 0; rt < 2; ++rt){
        #pragma unroll
        for (int rg = 0; rg < 16; ++rg){
          int rr  = (rg & 3) + 8*(rg >> 2) + 4*half;
          int row = rt*32 + rr;
          int el  = row*256 + (colm ^ ((rr & 7) << 3));
          hp[el] = (f16)fmaxf(aF[rt][rg] + f1bb, 0.0f);
        }
      }
    }
    LGKM0(); BARR();   // (FC1|FC2 + next pass A)

    // ---- FC2 (waves 0-1, one 32-row tile each); overlaps next step's pass A on waves 2-7 ----
    if (wu < 2){
      f32x16 a2 = 0.f;
      const int rb = wu * 8192;
      #pragma unroll
      for (int ks = 0; ks < 16; ++ks){
        f16x8 bv = *(const f16x8*)(gfc2 + (size_t)ks*512);
        f16x8 a0 = *(const f16x8*)(hp + ((abase + rb) ^ (ks << 4)));
        a2 = MFMA32(a0, bv, a2);
      }
      if (c32 < 2){
        #pragma unroll
        for (int rg = 0; rg < 16; ++rg){
          int rr = (rg & 3) + 8*(rg >> 2) + 4*half;
          out[((size_t)(r0 + wu*32 + rr)*32 + s)*2 + c32] = tanh_f(a2[rg] + f2bb);
        }
      }
    }
    // no trailing barrier: next iteration's (A|B) barrier fences FC2 vs pass-B writes
    { f16* tmp = hp; hp = hq; hq = tmp; }
  }
}

extern "C" void kernel_launch(void* const* d_in, const int* in_sizes, int n_in,
                              void* d_out, int out_size, void* d_ws, size_t ws_size,
                              hipStream_t stream)
{
  (void)in_sizes; (void)n_in; (void)out_size; (void)ws_size;
  const float* x    = (const float*)d_in[0];
  const float* emW  = (const float*)d_in[1];
  const float* emb_ = (const float*)d_in[2];
  const float* evW  = (const float*)d_in[3];
  const float* evb  = (const float*)d_in[4];
  const float* eWih = (const float*)d_in[5];
  const float* eWhh = (const float*)d_in[6];
  const float* ebih = (const float*)d_in[7];
  const float* ebhh = (const float*)d_in[8];
  const float* dWih = (const float*)d_in[9];
  const float* dWhh = (const float*)d_in[10];
  const float* dbih = (const float*)d_in[11];
  const float* dbhh = (const float*)d_in[12];
  const float* f1W  = (const float*)d_in[13];
  const float* f1b  = (const float*)d_in[14];
  const float* f2W  = (const float*)d_in[15];
  const float* f2b  = (const float*)d_in[16];
  float* out = (float*)d_out;
  f16* ws16 = (f16*)d_ws;

  prep_pack<<<(TOT_E + 255)/256, 256, 0, stream>>>(eWih, eWhh, dWih, dWhh, f1W, f2W, ws16);
  fused_net<<<NBLK, NTHR, 0, stream>>>(x, emW, emb_, evW, evb, ebih, ebhh,
                                       dbih, dbhh, f1b, f2b, ws16, out);
}